// Round 4
// baseline (319.835 us; speedup 1.0000x reference)
//
#include <hip/hip_runtime.h>
#include <cstdint>
#include <cstddef>

#define N_  8
#define C_  256
#define HW_ 1024
#define CL_ 16
#define SZ_ (N_*C_*HW_)   // 2,097,152 elements per tensor

typedef __attribute__((ext_vector_type(8))) _Float16 half8;
typedef __attribute__((ext_vector_type(4))) float f32x4;

static __device__ __forceinline__ float tanh_fast(float x){
  x = fminf(fmaxf(x, -15.f), 15.f);
  float e = __expf(2.f * x);
  return (e - 1.f) / (e + 1.f);
}

static __device__ __forceinline__ unsigned short f2h(float x){
  _Float16 h = (_Float16)x;
  return *(unsigned short*)&h;
}

// inline combine of 16 online-softmax partials -> (m, 1/sumexp); wave-uniform base
static __device__ __forceinline__ void combine16(
    const float* __restrict__ mpart, const float* __restrict__ spart,
    int base, float& m, float& rl)
{
  m = -1e30f;
  #pragma unroll
  for (int k = 0; k < 16; ++k) m = fmaxf(m, mpart[base * 16 + k]);
  float s = 0.f;
  #pragma unroll
  for (int k = 0; k < 16; ++k) s += spart[base * 16 + k] * __expf(mpart[base * 16 + k] - m);
  rl = 1.f / s;
}

#define GLD16(g, l) __builtin_amdgcn_global_load_lds( \
    (const __attribute__((address_space(1))) void*)(g), \
    (__attribute__((address_space(3))) void*)(l), 16, 0, 0)

// K1: cval[n,side,hw] = sum_c f[c,hw]*cw[c];  pdot[n,side,l,hw] = sum_c f[c,hw]*pw[l,c]
//     + per-block online-softmax partials (max, sumexp) of cval
__global__ __launch_bounds__(256) void k_sa_dot(
    const float* __restrict__ fp1, const float* __restrict__ fp2,
    const float* __restrict__ cw1, const float* __restrict__ cw2,
    const float* __restrict__ pw1, const float* __restrict__ pw2,
    float* __restrict__ cval, float* __restrict__ pdot,
    float* __restrict__ mpart, float* __restrict__ spart)
{
  const int n = blockIdx.z, side = blockIdx.y, hw0 = blockIdx.x * 64;
  const int t = threadIdx.x, hwl = t & 63, cg = t >> 6;
  const float* __restrict__ pw = side ? pw2 : pw1;
  const float* __restrict__ cw = side ? cw2 : cw1;
  const float* __restrict__ f  = (side ? fp2 : fp1) + (size_t)n * C_ * HW_ + hw0 + hwl;
  const int cb = __builtin_amdgcn_readfirstlane(cg * 64);

  float acc[17];
  #pragma unroll
  for (int l = 0; l < 17; ++l) acc[l] = 0.f;

  for (int cc = 0; cc < 64; ++cc){
    const int c = cb + cc;
    const float v = f[(size_t)c * HW_];
    acc[16] += v * cw[c];
    #pragma unroll
    for (int l = 0; l < 16; ++l) acc[l] += v * pw[l * C_ + c];
  }

  __shared__ float red[17][4][64];
  #pragma unroll
  for (int l = 0; l < 17; ++l) red[l][cg][hwl] = acc[l];
  __syncthreads();

  if (t < 64){
    const int base = n * 2 + side;
    float xc = 0.f;
    #pragma unroll
    for (int l = 0; l < 17; ++l){
      const float s = red[l][0][t] + red[l][1][t] + red[l][2][t] + red[l][3][t];
      if (l < 16) pdot[((size_t)base * CL_ + l) * HW_ + hw0 + t] = s;
      else      { cval[(size_t)base * HW_ + hw0 + t] = s; xc = s; }
    }
    float mb = xc;
    #pragma unroll
    for (int off = 32; off; off >>= 1) mb = fmaxf(mb, __shfl_xor(mb, off));
    float e = __expf(xc - mb);
    #pragma unroll
    for (int off = 32; off; off >>= 1) e += __shfl_xor(e, off);
    if (t == 0){
      mpart[base * 16 + blockIdx.x] = mb;
      spart[base * 16 + blockIdx.x] = e;
    }
  }
}

// K_xw: Xw (fp16) = w * f,  w = exp(cval - m) * rl
__global__ __launch_bounds__(256) void k_xw(
    const float* __restrict__ fp1, const float* __restrict__ fp2,
    const float* __restrict__ cval,
    const float* __restrict__ mpart, const float* __restrict__ spart,
    unsigned short* __restrict__ xw1, unsigned short* __restrict__ xw2)
{
  const int side = blockIdx.y;
  const size_t o = ((size_t)blockIdx.x * 256 + threadIdx.x) * 8;
  const float* __restrict__ f = side ? fp2 : fp1;
  unsigned short* __restrict__ xw = side ? xw2 : xw1;
  const int n = (int)(o >> 18), hw = (int)(o & (HW_ - 1));
  const int base = n * 2 + side;
  float m, rl;
  combine16(mpart, spart, base, m, rl);
  const float* cp = &cval[(size_t)base * HW_ + hw];
  const float4 c0 = *(const float4*)cp;
  const float4 c1 = *(const float4*)(cp + 4);
  const float4 v0 = *(const float4*)&f[o];
  const float4 v1 = *(const float4*)&f[o + 4];
  half8 r;
  r[0] = (_Float16)(v0.x * (__expf(c0.x - m) * rl));
  r[1] = (_Float16)(v0.y * (__expf(c0.y - m) * rl));
  r[2] = (_Float16)(v0.z * (__expf(c0.z - m) * rl));
  r[3] = (_Float16)(v0.w * (__expf(c0.w - m) * rl));
  r[4] = (_Float16)(v1.x * (__expf(c1.x - m) * rl));
  r[5] = (_Float16)(v1.y * (__expf(c1.y - m) * rl));
  r[6] = (_Float16)(v1.z * (__expf(c1.z - m) * rl));
  r[7] = (_Float16)(v1.w * (__expf(c1.w - m) * rl));
  *(half8*)&xw[o] = r;
}

// K2: A[n,i,j] = tanh( sum_l fcl2[l,i] * fcl1[l,j] ), fcl = w*pdot + pb inline.
//     Writes fp16 A (row-major i) and A^T (row-major j, LDS-staged coalesced).
__global__ __launch_bounds__(256) void k_corr(
    const float* __restrict__ cval, const float* __restrict__ pdot,
    const float* __restrict__ pb1, const float* __restrict__ pb2,
    const float* __restrict__ mpart, const float* __restrict__ spart,
    unsigned short* __restrict__ Abf, unsigned short* __restrict__ Atbf)
{
  const int n = blockIdx.z, i0 = blockIdx.y * 64, j0 = blockIdx.x * 64;
  const int b1 = n * 2, b2 = n * 2 + 1;
  __align__(16) __shared__ float s2[CL_][64];
  __align__(16) __shared__ float s1[CL_][64];
  __shared__ unsigned short at_s[64][68];
  const int t = threadIdx.x;
  const int lr = t >> 4, lc = (t & 15) * 4;

  float m1, rl1, m2, rl2;
  combine16(mpart, spart, b1, m1, rl1);
  combine16(mpart, spart, b2, m2, rl2);

  {
    const float bias2 = pb2[lr];
    const float4 c2 = *(const float4*)&cval[(size_t)b2 * HW_ + i0 + lc];
    const float4 p2 = *(const float4*)&pdot[((size_t)b2 * CL_ + lr) * HW_ + i0 + lc];
    s2[lr][lc + 0] = __expf(c2.x - m2) * rl2 * p2.x + bias2;
    s2[lr][lc + 1] = __expf(c2.y - m2) * rl2 * p2.y + bias2;
    s2[lr][lc + 2] = __expf(c2.z - m2) * rl2 * p2.z + bias2;
    s2[lr][lc + 3] = __expf(c2.w - m2) * rl2 * p2.w + bias2;

    const float bias1 = pb1[lr];
    const float4 c1 = *(const float4*)&cval[(size_t)b1 * HW_ + j0 + lc];
    const float4 p1 = *(const float4*)&pdot[((size_t)b1 * CL_ + lr) * HW_ + j0 + lc];
    s1[lr][lc + 0] = __expf(c1.x - m1) * rl1 * p1.x + bias1;
    s1[lr][lc + 1] = __expf(c1.y - m1) * rl1 * p1.y + bias1;
    s1[lr][lc + 2] = __expf(c1.z - m1) * rl1 * p1.z + bias1;
    s1[lr][lc + 3] = __expf(c1.w - m1) * rl1 * p1.w + bias1;
  }
  __syncthreads();

  const int ti = t >> 4, tj = t & 15;
  float acc[4][4];
  #pragma unroll
  for (int a = 0; a < 4; ++a)
    #pragma unroll
    for (int b = 0; b < 4; ++b) acc[a][b] = 0.f;

  #pragma unroll
  for (int l = 0; l < CL_; ++l){
    const float4 a4 = *(const float4*)&s2[l][ti * 4];
    const float4 b4 = *(const float4*)&s1[l][tj * 4];
    const float av[4] = {a4.x, a4.y, a4.z, a4.w};
    const float bv[4] = {b4.x, b4.y, b4.z, b4.w};
    #pragma unroll
    for (int a = 0; a < 4; ++a)
      #pragma unroll
      for (int b = 0; b < 4; ++b) acc[a][b] += av[a] * bv[b];
  }

  unsigned short tv[4][4];
  #pragma unroll
  for (int a = 0; a < 4; ++a)
    #pragma unroll
    for (int b = 0; b < 4; ++b) tv[a][b] = f2h(tanh_fast(acc[a][b]));

  unsigned short* __restrict__ An  = Abf  + ((size_t)n << 20);
  unsigned short* __restrict__ Atn = Atbf + ((size_t)n << 20);
  // A: direct coalesced rows (i-major)
  #pragma unroll
  for (int a = 0; a < 4; ++a){
    ushort4 va; va.x = tv[a][0]; va.y = tv[a][1]; va.z = tv[a][2]; va.w = tv[a][3];
    *(ushort4*)&An[(size_t)(i0 + ti * 4 + a) * HW_ + j0 + tj * 4] = va;
  }
  // A^T: stage transposed tile in LDS, then write full 128B rows
  #pragma unroll
  for (int b = 0; b < 4; ++b){
    ushort4 vb; vb.x = tv[0][b]; vb.y = tv[1][b]; vb.z = tv[2][b]; vb.w = tv[3][b];
    *(ushort4*)&at_s[tj * 4 + b][ti * 4] = vb;
  }
  __syncthreads();
  #pragma unroll
  for (int rep = 0; rep < 2; ++rep){
    const int idx = t + rep * 256;
    const int r = idx >> 3, q = (idx & 7) * 8;
    const ushort4 lo = *(const ushort4*)&at_s[r][q];
    const ushort4 hi = *(const ushort4*)&at_s[r][q + 4];
    *(ushort4*)&Atn[(size_t)(j0 + r) * HW_ + i0 + q] = lo;
    *(ushort4*)&Atn[(size_t)(j0 + r) * HW_ + i0 + q + 4] = hi;
  }
}

// K3: fused MFMA GEMM + channel-L2-norm + residual/ReLU.
// g=0: hat1[c,i] = sum_j Xw1[c,j]*A[i,j];  g=1: hat2[c,i] = sum_j Xw2[c,j]*A[j,i]
// BM=256 x BN=64 x BK=64, 512 thr / 8 waves. XCD-affine block mapping:
// all 16 i-tiles of a (n,g) pair land on one XCD so the X panel stays L2-resident.
__global__ __launch_bounds__(512) void k_gemm_fused(
    const unsigned short* __restrict__ xw1, const unsigned short* __restrict__ xw2,
    const unsigned short* __restrict__ Abf, const unsigned short* __restrict__ Atbf,
    const float* __restrict__ fpin1, const float* __restrict__ fpin2,
    float* __restrict__ fpo1, float* __restrict__ fpo2,
    float* __restrict__ out, int last)
{
  const int bx = blockIdx.x;
  const int p  = (bx & 7) | ((bx >> 7) << 3);   // pair id 0..15 -> XCD = p&7
  const int it = (bx >> 3) & 15;                // i-tile
  const int n = p >> 1, g = p & 1;
  const int i0 = it * 64;

  const unsigned short* __restrict__ X = (g ? xw2 : xw1) + (size_t)n * C_ * HW_;
  const unsigned short* __restrict__ B = (g ? Atbf : Abf) + ((size_t)n << 20);

  __shared__ unsigned short Xs[2][256 * 64];  // 2 x 32 KB
  __shared__ unsigned short Bs[2][64 * 64];   // 2 x 8 KB
  __shared__ float ssred[4][64];
  __shared__ float rinv[64];

  const int t = threadIdx.x, w = t >> 6, l = t & 63;
  const int wr = w >> 1, wc = w & 1;

  f32x4 acc[4][2];
  #pragma unroll
  for (int fm = 0; fm < 4; ++fm)
    #pragma unroll
    for (int fn = 0; fn < 2; ++fn)
      acc[fm][fn] = (f32x4){0.f, 0.f, 0.f, 0.f};

  auto stage = [&](int buf, int k0){
    #pragma unroll
    for (int s = 0; s < 4; ++s){
      const int q = (w * 4 + s) * 64 + l;
      const int row = q >> 3;
      const int kc = (q & 7) ^ (row & 7);
      GLD16(X + (size_t)row * HW_ + k0 + kc * 8, &Xs[buf][(w * 4 + s) * 512]);
    }
    {
      const int q = w * 64 + l;
      const int row = q >> 3;
      const int kc = (q & 7) ^ (row & 7);
      GLD16(B + (size_t)(i0 + row) * HW_ + k0 + kc * 8, &Bs[buf][w * 512]);
    }
  };

  stage(0, 0);
  __syncthreads();
  int cur = 0;
  for (int kt = 0; kt < 16; ++kt){
    if (kt < 15) stage(cur ^ 1, (kt + 1) * 64);
    #pragma unroll
    for (int ks = 0; ks < 2; ++ks){
      half8 a[4], b[2];
      #pragma unroll
      for (int fm = 0; fm < 4; ++fm){
        const int row = wr * 64 + fm * 16 + (l & 15);
        const int kc = (ks * 4 + (l >> 4)) ^ (row & 7);
        a[fm] = *(const half8*)&Xs[cur][row * 64 + kc * 8];
      }
      #pragma unroll
      for (int fn = 0; fn < 2; ++fn){
        const int row = wc * 32 + fn * 16 + (l & 15);
        const int kc = (ks * 4 + (l >> 4)) ^ (row & 7);
        b[fn] = *(const half8*)&Bs[cur][row * 64 + kc * 8];
      }
      #pragma unroll
      for (int fm = 0; fm < 4; ++fm)
        #pragma unroll
        for (int fn = 0; fn < 2; ++fn)
          acc[fm][fn] = __builtin_amdgcn_mfma_f32_16x16x32_f16(a[fm], b[fn], acc[fm][fn], 0, 0, 0);
    }
    __syncthreads();
    cur ^= 1;
  }

  // fused epilogue: column L2 norm over all 256 channels, then resid/relu or out
  float ss0 = 0.f, ss1 = 0.f;
  #pragma unroll
  for (int fm = 0; fm < 4; ++fm)
    #pragma unroll
    for (int r = 0; r < 4; ++r){
      ss0 += acc[fm][0][r] * acc[fm][0][r];
      ss1 += acc[fm][1][r] * acc[fm][1][r];
    }
  ss0 += __shfl_xor(ss0, 16); ss0 += __shfl_xor(ss0, 32);
  ss1 += __shfl_xor(ss1, 16); ss1 += __shfl_xor(ss1, 32);
  if (l < 16){
    ssred[wr][wc * 32 + l]      = ss0;
    ssred[wr][wc * 32 + 16 + l] = ss1;
  }
  __syncthreads();
  if (t < 64)
    rinv[t] = 1.f / fmaxf(sqrtf(ssred[0][t] + ssred[1][t] + ssred[2][t] + ssred[3][t]), 1e-12f);
  __syncthreads();

  const float ri[2] = { rinv[wc * 32 + (l & 15)], rinv[wc * 32 + 16 + (l & 15)] };

  const float* __restrict__ fpin = (g ? fpin2 : fpin1) + (size_t)n * C_ * HW_;
  float* __restrict__ fpo  = (g ? fpo2 : fpo1) + (size_t)n * C_ * HW_;
  float* __restrict__ outp = out + (size_t)g * SZ_ + (size_t)n * C_ * HW_;
  const int rbase = (l >> 4) * 4, col = l & 15;

  #pragma unroll
  for (int fm = 0; fm < 4; ++fm)
    #pragma unroll
    for (int fn = 0; fn < 2; ++fn){
      const size_t base = (size_t)(wr * 64 + fm * 16 + rbase) * HW_ + i0 + wc * 32 + fn * 16 + col;
      #pragma unroll
      for (int r = 0; r < 4; ++r){
        const float h = acc[fm][fn][r] * ri[fn];
        if (last) outp[base + (size_t)r * HW_] = h;
        else {
          const float fv = fpin[base + (size_t)r * HW_] + h;
          fpo[base + (size_t)r * HW_] = fv > 0.f ? fv : 0.f;
        }
      }
    }
}

// K_s: s[n,c,hw] = w * fp,  w = exp(cval - m) * rl
__global__ __launch_bounds__(256) void k_s_out(
    const float* __restrict__ fp1, const float* __restrict__ fp2,
    const float* __restrict__ cval,
    const float* __restrict__ mpart, const float* __restrict__ spart,
    float* __restrict__ out)
{
  const int side = blockIdx.y;
  const size_t fo = ((size_t)blockIdx.x * 256 + threadIdx.x) * 4;
  const float* __restrict__ f = side ? fp2 : fp1;
  const int n  = (int)(fo >> 18);
  const int hw = (int)(fo & (HW_ - 1));
  const int base = n * 2 + side;
  float m, rl;
  combine16(mpart, spart, base, m, rl);
  const float4 c = *(const float4*)&cval[(size_t)base * HW_ + hw];
  const float4 v = *(const float4*)&f[fo];
  float4 r;
  r.x = v.x * (__expf(c.x - m) * rl);
  r.y = v.y * (__expf(c.y - m) * rl);
  r.z = v.z * (__expf(c.z - m) * rl);
  r.w = v.w * (__expf(c.w - m) * rl);
  *(float4*)&out[(size_t)(2 + side) * SZ_ + fo] = r;
}

extern "C" void kernel_launch(void* const* d_in, const int* in_sizes, int n_in,
                              void* d_out, int out_size, void* d_ws, size_t ws_size,
                              hipStream_t stream)
{
  const float* f1  = (const float*)d_in[0];
  const float* f2  = (const float*)d_in[1];
  const float* pw1 = (const float*)d_in[2];
  const float* pb1 = (const float*)d_in[3];
  const float* pw2 = (const float*)d_in[4];
  const float* pb2 = (const float*)d_in[5];
  const float* cw1 = (const float*)d_in[6];
  const float* cw2 = (const float*)d_in[8];
  // cb1/cb2 unused: softmax is shift-invariant
  float* out = (float*)d_out;
  float* ws  = (float*)d_ws;

  float* fp1   = ws;                           // SZ_ f32
  float* fp2   = fp1  + SZ_;                   // SZ_ f32
  float* cval  = fp2  + SZ_;                   // 16K f32
  float* pdot  = cval + N_ * 2 * HW_;          // 256K f32
  float* mpart = pdot + N_ * 2 * CL_ * HW_;    // 512
  float* spart = mpart + 512;                  // 512
  unsigned short* xw1  = (unsigned short*)(spart + 512); // SZ_ fp16
  unsigned short* xw2  = xw1 + SZ_;                      // SZ_ fp16
  unsigned short* Abf  = xw2 + SZ_;                      // 8M fp16
  unsigned short* Atbf = Abf + ((size_t)N_ << 20);       // 8M fp16

  for (int it = 0; it < 5; ++it){
    const float* cur1 = (it == 0) ? f1 : fp1;
    const float* cur2 = (it == 0) ? f2 : fp2;

    k_sa_dot<<<dim3(16, 2, 8), 256, 0, stream>>>(cur1, cur2, cw1, cw2, pw1, pw2,
                                                 cval, pdot, mpart, spart);
    k_xw<<<dim3(SZ_ / 8 / 256, 2), 256, 0, stream>>>(cur1, cur2, cval, mpart, spart, xw1, xw2);
    if (it == 4)
      k_s_out<<<dim3(SZ_ / 4 / 256, 2), 256, 0, stream>>>(cur1, cur2, cval, mpart, spart, out);
    k_corr<<<dim3(16, 16, 8), 256, 0, stream>>>(cval, pdot, pb1, pb2, mpart, spart, Abf, Atbf);
    k_gemm_fused<<<dim3(256), 512, 0, stream>>>(xw1, xw2, Abf, Atbf,
                                                cur1, cur2, fp1, fp2, out, (it == 4) ? 1 : 0);
  }
}

// Round 7
// 310.316 us; speedup vs baseline: 1.0307x; 1.0307x over previous
//
#include <hip/hip_runtime.h>
#include <cstdint>
#include <cstddef>

#define N_  8
#define C_  256
#define HW_ 1024
#define CL_ 16
#define SZ_ (N_*C_*HW_)   // 2,097,152 elements per tensor
#define WSCALE_ 4096.0f   // 2^12, exact in fp: folded into A, divides out in L2-norm

typedef __attribute__((ext_vector_type(8))) _Float16 half8;
typedef __attribute__((ext_vector_type(4))) float f32x4;

static __device__ __forceinline__ float tanh_fast(float x){
  x = fminf(fmaxf(x, -15.f), 15.f);
  float e = __expf(2.f * x);
  return (e - 1.f) / (e + 1.f);
}

static __device__ __forceinline__ unsigned short f2h(float x){
  _Float16 h = (_Float16)x;
  return *(unsigned short*)&h;
}

// inline combine of 16 online-softmax partials -> (m, 1/sumexp)
static __device__ __forceinline__ void combine16(
    const float* __restrict__ mpart, const float* __restrict__ spart,
    int base, float& m, float& rl)
{
  m = -1e30f;
  #pragma unroll
  for (int k = 0; k < 16; ++k) m = fmaxf(m, mpart[base * 16 + k]);
  float s = 0.f;
  #pragma unroll
  for (int k = 0; k < 16; ++k) s += spart[base * 16 + k] * __expf(mpart[base * 16 + k] - m);
  rl = 1.f / s;
}

#define GLD16(g, l) __builtin_amdgcn_global_load_lds( \
    (const __attribute__((address_space(1))) void*)(g), \
    (__attribute__((address_space(3))) void*)(l), 16, 0, 0)

// K0: one-time fp32 -> fp16 mirror of the input features (GEMM X operand, iter 0)
__global__ __launch_bounds__(256) void k_cvt(
    const float* __restrict__ f1, const float* __restrict__ f2,
    _Float16* __restrict__ o1, _Float16* __restrict__ o2)
{
  const int side = blockIdx.y;
  const size_t o = ((size_t)blockIdx.x * 256 + threadIdx.x) * 8;
  const float* __restrict__ f = side ? f2 : f1;
  _Float16* __restrict__ oo = side ? o2 : o1;
  const float4 v0 = *(const float4*)&f[o];
  const float4 v1 = *(const float4*)&f[o + 4];
  half8 r;
  r[0] = (_Float16)v0.x; r[1] = (_Float16)v0.y; r[2] = (_Float16)v0.z; r[3] = (_Float16)v0.w;
  r[4] = (_Float16)v1.x; r[5] = (_Float16)v1.y; r[6] = (_Float16)v1.z; r[7] = (_Float16)v1.w;
  *(half8*)&oo[o] = r;
}

// K1: cval[n,side,hw] = sum_c f[c,hw]*cw[c];  pdot[n,side,l,hw] = sum_c f[c,hw]*pw[l,c]
//     + per-block online-softmax partials (max, sumexp). f = fp32 state.
__global__ __launch_bounds__(256) void k_sa_dot(
    const float* __restrict__ fp1, const float* __restrict__ fp2,
    const float* __restrict__ cw1, const float* __restrict__ cw2,
    const float* __restrict__ pw1, const float* __restrict__ pw2,
    float* __restrict__ cval, float* __restrict__ pdot,
    float* __restrict__ mpart, float* __restrict__ spart)
{
  const int n = blockIdx.z, side = blockIdx.y, hw0 = blockIdx.x * 64;
  const int t = threadIdx.x, hwl = t & 63, cg = t >> 6;
  const float* __restrict__ pw = side ? pw2 : pw1;
  const float* __restrict__ cw = side ? cw2 : cw1;
  const float* __restrict__ f  = (side ? fp2 : fp1) + (size_t)n * C_ * HW_ + hw0 + hwl;
  const int cb = __builtin_amdgcn_readfirstlane(cg * 64);

  float acc[17];
  #pragma unroll
  for (int l = 0; l < 17; ++l) acc[l] = 0.f;

  for (int cc = 0; cc < 64; ++cc){
    const int c = cb + cc;
    const float v = f[(size_t)c * HW_];
    acc[16] += v * cw[c];
    #pragma unroll
    for (int l = 0; l < 16; ++l) acc[l] += v * pw[l * C_ + c];
  }

  __shared__ float red[17][4][64];
  #pragma unroll
  for (int l = 0; l < 17; ++l) red[l][cg][hwl] = acc[l];
  __syncthreads();

  if (t < 64){
    const int base = n * 2 + side;
    float xc = 0.f;
    #pragma unroll
    for (int l = 0; l < 17; ++l){
      const float s = red[l][0][t] + red[l][1][t] + red[l][2][t] + red[l][3][t];
      if (l < 16) pdot[((size_t)base * CL_ + l) * HW_ + hw0 + t] = s;
      else      { cval[(size_t)base * HW_ + hw0 + t] = s; xc = s; }
    }
    float mb = xc;
    #pragma unroll
    for (int off = 32; off; off >>= 1) mb = fmaxf(mb, __shfl_xor(mb, off));
    float e = __expf(xc - mb);
    #pragma unroll
    for (int off = 32; off; off >>= 1) e += __shfl_xor(e, off);
    if (t == 0){
      mpart[base * 16 + blockIdx.x] = mb;
      spart[base * 16 + blockIdx.x] = e;
    }
  }
}

// K2: A[n,i,j] = tanh( sum_l fcl2[l,i] * fcl1[l,j] ), fcl = w*pdot + pb inline.
//     Writes SCALED-w-folded fp16 tiles (s = 2^12, exact; normalized away in epilogue):
//       Abf[i][j] = s*w1[j]*A[i][j]   (g=0 B-operand)
//       Atn[u][v] = s*w2[v]*A[v][u]   (g=1 B-operand, LDS-staged coalesced)
__global__ __launch_bounds__(256) void k_corr(
    const float* __restrict__ cval, const float* __restrict__ pdot,
    const float* __restrict__ pb1, const float* __restrict__ pb2,
    const float* __restrict__ mpart, const float* __restrict__ spart,
    unsigned short* __restrict__ Abf, unsigned short* __restrict__ Atbf)
{
  const int n = blockIdx.z, i0 = blockIdx.y * 64, j0 = blockIdx.x * 64;
  const int b1 = n * 2, b2 = n * 2 + 1;
  __align__(16) __shared__ float s2[CL_][64];
  __align__(16) __shared__ float s1[CL_][64];
  __shared__ unsigned short at_s[64][68];
  const int t = threadIdx.x;
  const int lr = t >> 4, lc = (t & 15) * 4;

  float m1, rl1, m2, rl2;
  combine16(mpart, spart, b1, m1, rl1);
  combine16(mpart, spart, b2, m2, rl2);

  {
    const float bias2 = pb2[lr];
    const float4 c2 = *(const float4*)&cval[(size_t)b2 * HW_ + i0 + lc];
    const float4 p2 = *(const float4*)&pdot[((size_t)b2 * CL_ + lr) * HW_ + i0 + lc];
    s2[lr][lc + 0] = __expf(c2.x - m2) * rl2 * p2.x + bias2;
    s2[lr][lc + 1] = __expf(c2.y - m2) * rl2 * p2.y + bias2;
    s2[lr][lc + 2] = __expf(c2.z - m2) * rl2 * p2.z + bias2;
    s2[lr][lc + 3] = __expf(c2.w - m2) * rl2 * p2.w + bias2;

    const float bias1 = pb1[lr];
    const float4 c1 = *(const float4*)&cval[(size_t)b1 * HW_ + j0 + lc];
    const float4 p1 = *(const float4*)&pdot[((size_t)b1 * CL_ + lr) * HW_ + j0 + lc];
    s1[lr][lc + 0] = __expf(c1.x - m1) * rl1 * p1.x + bias1;
    s1[lr][lc + 1] = __expf(c1.y - m1) * rl1 * p1.y + bias1;
    s1[lr][lc + 2] = __expf(c1.z - m1) * rl1 * p1.z + bias1;
    s1[lr][lc + 3] = __expf(c1.w - m1) * rl1 * p1.w + bias1;
  }
  __syncthreads();

  const int ti = t >> 4, tj = t & 15;
  float acc[4][4];
  #pragma unroll
  for (int a = 0; a < 4; ++a)
    #pragma unroll
    for (int b = 0; b < 4; ++b) acc[a][b] = 0.f;

  #pragma unroll
  for (int l = 0; l < CL_; ++l){
    const float4 a4 = *(const float4*)&s2[l][ti * 4];
    const float4 b4 = *(const float4*)&s1[l][tj * 4];
    const float av[4] = {a4.x, a4.y, a4.z, a4.w};
    const float bv[4] = {b4.x, b4.y, b4.z, b4.w};
    #pragma unroll
    for (int a = 0; a < 4; ++a)
      #pragma unroll
      for (int b = 0; b < 4; ++b) acc[a][b] += av[a] * bv[b];
  }

  float tf[4][4];
  #pragma unroll
  for (int a = 0; a < 4; ++a)
    #pragma unroll
    for (int b = 0; b < 4; ++b) tf[a][b] = tanh_fast(acc[a][b]);

  // scaled softmax weights at the j-columns (w1) and i-columns (w2)
  float w1j[4], w2i[4];
  #pragma unroll
  for (int b = 0; b < 4; ++b)
    w1j[b] = WSCALE_ * __expf(cval[(size_t)b1 * HW_ + j0 + tj * 4 + b] - m1) * rl1;
  #pragma unroll
  for (int a = 0; a < 4; ++a)
    w2i[a] = WSCALE_ * __expf(cval[(size_t)b2 * HW_ + i0 + ti * 4 + a] - m2) * rl2;

  unsigned short* __restrict__ An  = Abf  + ((size_t)n << 20);
  unsigned short* __restrict__ Atn = Atbf + ((size_t)n << 20);
  // Abf[i][j] = s*w1[j]*A[i][j] : direct coalesced rows
  #pragma unroll
  for (int a = 0; a < 4; ++a){
    ushort4 va;
    va.x = f2h(tf[a][0] * w1j[0]); va.y = f2h(tf[a][1] * w1j[1]);
    va.z = f2h(tf[a][2] * w1j[2]); va.w = f2h(tf[a][3] * w1j[3]);
    *(ushort4*)&An[(size_t)(i0 + ti * 4 + a) * HW_ + j0 + tj * 4] = va;
  }
  // Atn[u=j][v=i] = s*w2[i]*A[i][j] : stage in LDS, write full rows
  #pragma unroll
  for (int b = 0; b < 4; ++b){
    ushort4 vb;
    vb.x = f2h(tf[0][b] * w2i[0]); vb.y = f2h(tf[1][b] * w2i[1]);
    vb.z = f2h(tf[2][b] * w2i[2]); vb.w = f2h(tf[3][b] * w2i[3]);
    *(ushort4*)&at_s[tj * 4 + b][ti * 4] = vb;
  }
  __syncthreads();
  #pragma unroll
  for (int rep = 0; rep < 2; ++rep){
    const int idx = t + rep * 256;
    const int r = idx >> 3, q = (idx & 7) * 8;
    const ushort4 lo = *(const ushort4*)&at_s[r][q];
    const ushort4 hi = *(const ushort4*)&at_s[r][q + 4];
    *(ushort4*)&Atn[(size_t)(j0 + r) * HW_ + i0 + q] = lo;
    *(ushort4*)&Atn[(size_t)(j0 + r) * HW_ + i0 + q + 4] = hi;
  }
}

// K3: fused MFMA GEMM + channel-L2-norm + residual/ReLU.
// X operand = plain fp16 mirror of the state; w lives (scaled) in the B operand.
// g=0: s*hat1[c,i] = sum_j fh1[c,j]*(s*w1[j]*A[i,j]);  g=1 analogous with Atbf.
// Scale s cancels in the L2-norm. fp32 state read for residual; epilogue writes
// fp32 next-state AND its fp16 mirror (ping-pong, no cross-block race).
__global__ __launch_bounds__(512) void k_gemm_fused(
    const _Float16* __restrict__ fhc1, const _Float16* __restrict__ fhc2,
    const unsigned short* __restrict__ Abf, const unsigned short* __restrict__ Atbf,
    const float* __restrict__ fpin1, const float* __restrict__ fpin2,
    float* __restrict__ fpo1, float* __restrict__ fpo2,
    _Float16* __restrict__ fhn1, _Float16* __restrict__ fhn2,
    float* __restrict__ out, int last)
{
  const int n = blockIdx.z, g = blockIdx.y, i0 = blockIdx.x * 64;
  const unsigned short* __restrict__ X =
      (const unsigned short*)((g ? fhc2 : fhc1) + (size_t)n * C_ * HW_);
  const unsigned short* __restrict__ B = (g ? Atbf : Abf) + ((size_t)n << 20);

  __shared__ unsigned short Xs[2][256 * 64];  // 2 x 32 KB
  __shared__ unsigned short Bs[2][64 * 64];   // 2 x 8 KB
  __shared__ float ssred[4][64];
  __shared__ float rinv[64];

  const int t = threadIdx.x, w = t >> 6, l = t & 63;
  const int wr = w >> 1, wc = w & 1;

  f32x4 acc[4][2];
  #pragma unroll
  for (int fm = 0; fm < 4; ++fm)
    #pragma unroll
    for (int fn = 0; fn < 2; ++fn)
      acc[fm][fn] = (f32x4){0.f, 0.f, 0.f, 0.f};

  auto stage = [&](int buf, int k0){
    #pragma unroll
    for (int s = 0; s < 4; ++s){
      const int q = (w * 4 + s) * 64 + l;
      const int row = q >> 3;
      const int kc = (q & 7) ^ (row & 7);
      GLD16(X + (size_t)row * HW_ + k0 + kc * 8, &Xs[buf][(w * 4 + s) * 512]);
    }
    {
      const int q = w * 64 + l;
      const int row = q >> 3;
      const int kc = (q & 7) ^ (row & 7);
      GLD16(B + (size_t)(i0 + row) * HW_ + k0 + kc * 8, &Bs[buf][w * 512]);
    }
  };

  stage(0, 0);
  __syncthreads();
  int cur = 0;
  for (int kt = 0; kt < 16; ++kt){
    if (kt < 15) stage(cur ^ 1, (kt + 1) * 64);
    #pragma unroll
    for (int ks = 0; ks < 2; ++ks){
      half8 a[4], b[2];
      #pragma unroll
      for (int fm = 0; fm < 4; ++fm){
        const int row = wr * 64 + fm * 16 + (l & 15);
        const int kc = (ks * 4 + (l >> 4)) ^ (row & 7);
        a[fm] = *(const half8*)&Xs[cur][row * 64 + kc * 8];
      }
      #pragma unroll
      for (int fn = 0; fn < 2; ++fn){
        const int row = wc * 32 + fn * 16 + (l & 15);
        const int kc = (ks * 4 + (l >> 4)) ^ (row & 7);
        b[fn] = *(const half8*)&Bs[cur][row * 64 + kc * 8];
      }
      #pragma unroll
      for (int fm = 0; fm < 4; ++fm)
        #pragma unroll
        for (int fn = 0; fn < 2; ++fn)
          acc[fm][fn] = __builtin_amdgcn_mfma_f32_16x16x32_f16(a[fm], b[fn], acc[fm][fn], 0, 0, 0);
    }
    __syncthreads();
    cur ^= 1;
  }

  // fused epilogue: column L2 norm over all 256 channels (scale s cancels)
  float ss0 = 0.f, ss1 = 0.f;
  #pragma unroll
  for (int fm = 0; fm < 4; ++fm)
    #pragma unroll
    for (int r = 0; r < 4; ++r){
      ss0 += acc[fm][0][r] * acc[fm][0][r];
      ss1 += acc[fm][1][r] * acc[fm][1][r];
    }
  ss0 += __shfl_xor(ss0, 16); ss0 += __shfl_xor(ss0, 32);
  ss1 += __shfl_xor(ss1, 16); ss1 += __shfl_xor(ss1, 32);
  if (l < 16){
    ssred[wr][wc * 32 + l]      = ss0;
    ssred[wr][wc * 32 + 16 + l] = ss1;
  }
  __syncthreads();
  if (t < 64)
    rinv[t] = 1.f / fmaxf(sqrtf(ssred[0][t] + ssred[1][t] + ssred[2][t] + ssred[3][t]), 1e-12f);
  __syncthreads();

  const float ri[2] = { rinv[wc * 32 + (l & 15)], rinv[wc * 32 + 16 + (l & 15)] };

  const float* __restrict__ fpin = (g ? fpin2 : fpin1) + (size_t)n * C_ * HW_;
  float* __restrict__ fpo  = (g ? fpo2 : fpo1) + (size_t)n * C_ * HW_;
  _Float16* __restrict__ fhn = (g ? fhn2 : fhn1) + (size_t)n * C_ * HW_;
  float* __restrict__ outp = out + (size_t)g * SZ_ + (size_t)n * C_ * HW_;
  const int rbase = (l >> 4) * 4, col = l & 15;

  #pragma unroll
  for (int fm = 0; fm < 4; ++fm)
    #pragma unroll
    for (int fn = 0; fn < 2; ++fn){
      const size_t base = (size_t)(wr * 64 + fm * 16 + rbase) * HW_ + i0 + wc * 32 + fn * 16 + col;
      #pragma unroll
      for (int r = 0; r < 4; ++r){
        const float h = acc[fm][fn][r] * ri[fn];
        if (last) outp[base + (size_t)r * HW_] = h;
        else {
          const float fv = fpin[base + (size_t)r * HW_] + h;
          const float rv = fv > 0.f ? fv : 0.f;
          fpo[base + (size_t)r * HW_] = rv;
          fhn[base + (size_t)r * HW_] = (_Float16)rv;
        }
      }
    }
}

// K_s: s[n,c,hw] = w * fp (fp32 state),  w = exp(cval - m) * rl
__global__ __launch_bounds__(256) void k_s_out(
    const float* __restrict__ fp1, const float* __restrict__ fp2,
    const float* __restrict__ cval,
    const float* __restrict__ mpart, const float* __restrict__ spart,
    float* __restrict__ out)
{
  const int side = blockIdx.y;
  const size_t fo = ((size_t)blockIdx.x * 256 + threadIdx.x) * 4;
  const float* __restrict__ f = side ? fp2 : fp1;
  const int n  = (int)(fo >> 18);
  const int hw = (int)(fo & (HW_ - 1));
  const int base = n * 2 + side;
  float m, rl;
  combine16(mpart, spart, base, m, rl);
  const float4 c = *(const float4*)&cval[(size_t)base * HW_ + hw];
  const float4 v = *(const float4*)&f[fo];
  float4 r;
  r.x = v.x * (__expf(c.x - m) * rl);
  r.y = v.y * (__expf(c.y - m) * rl);
  r.z = v.z * (__expf(c.z - m) * rl);
  r.w = v.w * (__expf(c.w - m) * rl);
  *(float4*)&out[(size_t)(2 + side) * SZ_ + fo] = r;
}

extern "C" void kernel_launch(void* const* d_in, const int* in_sizes, int n_in,
                              void* d_out, int out_size, void* d_ws, size_t ws_size,
                              hipStream_t stream)
{
  const float* f1  = (const float*)d_in[0];
  const float* f2  = (const float*)d_in[1];
  const float* pw1 = (const float*)d_in[2];
  const float* pb1 = (const float*)d_in[3];
  const float* pw2 = (const float*)d_in[4];
  const float* pb2 = (const float*)d_in[5];
  const float* cw1 = (const float*)d_in[6];
  const float* cw2 = (const float*)d_in[8];
  // cb1/cb2 unused: softmax is shift-invariant
  float* out = (float*)d_out;
  float* ws  = (float*)d_ws;

  float* cval  = ws;                           // 16K f32
  float* pdot  = cval + N_ * 2 * HW_;          // 256K f32
  float* mpart = pdot + N_ * 2 * CL_ * HW_;    // 512
  float* spart = mpart + 512;                  // 512
  float* fp1   = spart + 512;                  // SZ_ f32 state
  float* fp2   = fp1 + SZ_;                    // SZ_ f32 state
  _Float16* fhA1 = (_Float16*)(fp2 + SZ_);     // SZ_ fp16 mirror (ping)
  _Float16* fhA2 = fhA1 + SZ_;
  _Float16* fhB1 = fhA2 + SZ_;                 // SZ_ fp16 mirror (pong)
  _Float16* fhB2 = fhB1 + SZ_;
  unsigned short* Abf  = (unsigned short*)(fhB2 + SZ_);  // 8M fp16
  unsigned short* Atbf = Abf + ((size_t)N_ << 20);       // 8M fp16

  k_cvt<<<dim3(SZ_ / 8 / 256, 2), 256, 0, stream>>>(f1, f2, fhA1, fhA2);

  for (int it = 0; it < 5; ++it){
    const float* cur1 = (it == 0) ? f1 : fp1;
    const float* cur2 = (it == 0) ? f2 : fp2;
    const _Float16* fhc1 = (it & 1) ? fhB1 : fhA1;
    const _Float16* fhc2 = (it & 1) ? fhB2 : fhA2;
    _Float16* fhn1 = (it & 1) ? fhA1 : fhB1;
    _Float16* fhn2 = (it & 1) ? fhA2 : fhB2;

    k_sa_dot<<<dim3(16, 2, 8), 256, 0, stream>>>(cur1, cur2, cw1, cw2, pw1, pw2,
                                                 cval, pdot, mpart, spart);
    if (it == 4)
      k_s_out<<<dim3(SZ_ / 4 / 256, 2), 256, 0, stream>>>(cur1, cur2, cval, mpart, spart, out);
    k_corr<<<dim3(16, 16, 8), 256, 0, stream>>>(cval, pdot, pb1, pb2, mpart, spart, Abf, Atbf);
    k_gemm_fused<<<dim3(16, 2, 8), 512, 0, stream>>>(fhc1, fhc2, Abf, Atbf,
                                                     cur1, cur2, fp1, fp2, fhn1, fhn2,
                                                     out, (it == 4) ? 1 : 0);
  }
}

// Round 8
// 308.428 us; speedup vs baseline: 1.0370x; 1.0061x over previous
//
#include <hip/hip_runtime.h>
#include <cstdint>
#include <cstddef>

#define N_  8
#define C_  256
#define HW_ 1024
#define CL_ 16
#define SZ_ (N_*C_*HW_)   // 2,097,152 elements per tensor
#define WSCALE_ 4096.0f   // 2^12, exact in fp: folded into A, divides out in L2-norm

typedef __attribute__((ext_vector_type(8))) _Float16 half8;
typedef __attribute__((ext_vector_type(4))) float f32x4;

static __device__ __forceinline__ float tanh_fast(float x){
  x = fminf(fmaxf(x, -15.f), 15.f);
  float e = __expf(2.f * x);
  return (e - 1.f) / (e + 1.f);
}

static __device__ __forceinline__ unsigned short f2h(float x){
  _Float16 h = (_Float16)x;
  return *(unsigned short*)&h;
}

// inline combine of 16 online-softmax partials -> (m, 1/sumexp)
static __device__ __forceinline__ void combine16(
    const float* __restrict__ mpart, const float* __restrict__ spart,
    int base, float& m, float& rl)
{
  m = -1e30f;
  #pragma unroll
  for (int k = 0; k < 16; ++k) m = fmaxf(m, mpart[base * 16 + k]);
  float s = 0.f;
  #pragma unroll
  for (int k = 0; k < 16; ++k) s += spart[base * 16 + k] * __expf(mpart[base * 16 + k] - m);
  rl = 1.f / s;
}

#define GLD16(g, l) __builtin_amdgcn_global_load_lds( \
    (const __attribute__((address_space(1))) void*)(g), \
    (__attribute__((address_space(3))) void*)(l), 16, 0, 0)

// K0: one-time fp32 -> fp16 mirror of the input features (GEMM X operand, iter 0)
__global__ __launch_bounds__(256) void k_cvt(
    const float* __restrict__ f1, const float* __restrict__ f2,
    _Float16* __restrict__ o1, _Float16* __restrict__ o2)
{
  const int side = blockIdx.y;
  const size_t o = ((size_t)blockIdx.x * 256 + threadIdx.x) * 8;
  const float* __restrict__ f = side ? f2 : f1;
  _Float16* __restrict__ oo = side ? o2 : o1;
  const float4 v0 = *(const float4*)&f[o];
  const float4 v1 = *(const float4*)&f[o + 4];
  half8 r;
  r[0] = (_Float16)v0.x; r[1] = (_Float16)v0.y; r[2] = (_Float16)v0.z; r[3] = (_Float16)v0.w;
  r[4] = (_Float16)v1.x; r[5] = (_Float16)v1.y; r[6] = (_Float16)v1.z; r[7] = (_Float16)v1.w;
  *(half8*)&oo[o] = r;
}

// K1: cval[n,side,hw] = sum_c f[c,hw]*cw[c];  pdot[n,side,l,hw] = sum_c f[c,hw]*pw[l,c]
//     + per-block online-softmax partials (max, sumexp). f = fp32 state.
__global__ __launch_bounds__(256) void k_sa_dot(
    const float* __restrict__ fp1, const float* __restrict__ fp2,
    const float* __restrict__ cw1, const float* __restrict__ cw2,
    const float* __restrict__ pw1, const float* __restrict__ pw2,
    float* __restrict__ cval, float* __restrict__ pdot,
    float* __restrict__ mpart, float* __restrict__ spart)
{
  const int n = blockIdx.z, side = blockIdx.y, hw0 = blockIdx.x * 64;
  const int t = threadIdx.x, hwl = t & 63, cg = t >> 6;
  const float* __restrict__ pw = side ? pw2 : pw1;
  const float* __restrict__ cw = side ? cw2 : cw1;
  const float* __restrict__ f  = (side ? fp2 : fp1) + (size_t)n * C_ * HW_ + hw0 + hwl;
  const int cb = __builtin_amdgcn_readfirstlane(cg * 64);

  float acc[17];
  #pragma unroll
  for (int l = 0; l < 17; ++l) acc[l] = 0.f;

  for (int cc = 0; cc < 64; ++cc){
    const int c = cb + cc;
    const float v = f[(size_t)c * HW_];
    acc[16] += v * cw[c];
    #pragma unroll
    for (int l = 0; l < 16; ++l) acc[l] += v * pw[l * C_ + c];
  }

  __shared__ float red[17][4][64];
  #pragma unroll
  for (int l = 0; l < 17; ++l) red[l][cg][hwl] = acc[l];
  __syncthreads();

  if (t < 64){
    const int base = n * 2 + side;
    float xc = 0.f;
    #pragma unroll
    for (int l = 0; l < 17; ++l){
      const float s = red[l][0][t] + red[l][1][t] + red[l][2][t] + red[l][3][t];
      if (l < 16) pdot[((size_t)base * CL_ + l) * HW_ + hw0 + t] = s;
      else      { cval[(size_t)base * HW_ + hw0 + t] = s; xc = s; }
    }
    float mb = xc;
    #pragma unroll
    for (int off = 32; off; off >>= 1) mb = fmaxf(mb, __shfl_xor(mb, off));
    float e = __expf(xc - mb);
    #pragma unroll
    for (int off = 32; off; off >>= 1) e += __shfl_xor(e, off);
    if (t == 0){
      mpart[base * 16 + blockIdx.x] = mb;
      spart[base * 16 + blockIdx.x] = e;
    }
  }
}

// K2: A[n,i,j] = tanh( sum_l fcl2[l,i] * fcl1[l,j] ), fcl = w*pdot + pb inline.
//     Writes SCALED-w-folded fp16 tiles (s = 2^12, exact; normalized away in epilogue):
//       Abf[i][j] = s*w1[j]*A[i][j]   (g=0 B-operand)
//       Atn[u][v] = s*w2[v]*A[v][u]   (g=1 B-operand, LDS-staged coalesced)
__global__ __launch_bounds__(256) void k_corr(
    const float* __restrict__ cval, const float* __restrict__ pdot,
    const float* __restrict__ pb1, const float* __restrict__ pb2,
    const float* __restrict__ mpart, const float* __restrict__ spart,
    unsigned short* __restrict__ Abf, unsigned short* __restrict__ Atbf)
{
  const int n = blockIdx.z, i0 = blockIdx.y * 64, j0 = blockIdx.x * 64;
  const int b1 = n * 2, b2 = n * 2 + 1;
  __align__(16) __shared__ float s2[CL_][64];
  __align__(16) __shared__ float s1[CL_][64];
  __shared__ unsigned short at_s[64][68];
  const int t = threadIdx.x;
  const int lr = t >> 4, lc = (t & 15) * 4;

  float m1, rl1, m2, rl2;
  combine16(mpart, spart, b1, m1, rl1);
  combine16(mpart, spart, b2, m2, rl2);

  {
    const float bias2 = pb2[lr];
    const float4 c2 = *(const float4*)&cval[(size_t)b2 * HW_ + i0 + lc];
    const float4 p2 = *(const float4*)&pdot[((size_t)b2 * CL_ + lr) * HW_ + i0 + lc];
    s2[lr][lc + 0] = __expf(c2.x - m2) * rl2 * p2.x + bias2;
    s2[lr][lc + 1] = __expf(c2.y - m2) * rl2 * p2.y + bias2;
    s2[lr][lc + 2] = __expf(c2.z - m2) * rl2 * p2.z + bias2;
    s2[lr][lc + 3] = __expf(c2.w - m2) * rl2 * p2.w + bias2;

    const float bias1 = pb1[lr];
    const float4 c1 = *(const float4*)&cval[(size_t)b1 * HW_ + j0 + lc];
    const float4 p1 = *(const float4*)&pdot[((size_t)b1 * CL_ + lr) * HW_ + j0 + lc];
    s1[lr][lc + 0] = __expf(c1.x - m1) * rl1 * p1.x + bias1;
    s1[lr][lc + 1] = __expf(c1.y - m1) * rl1 * p1.y + bias1;
    s1[lr][lc + 2] = __expf(c1.z - m1) * rl1 * p1.z + bias1;
    s1[lr][lc + 3] = __expf(c1.w - m1) * rl1 * p1.w + bias1;
  }
  __syncthreads();

  const int ti = t >> 4, tj = t & 15;
  float acc[4][4];
  #pragma unroll
  for (int a = 0; a < 4; ++a)
    #pragma unroll
    for (int b = 0; b < 4; ++b) acc[a][b] = 0.f;

  #pragma unroll
  for (int l = 0; l < CL_; ++l){
    const float4 a4 = *(const float4*)&s2[l][ti * 4];
    const float4 b4 = *(const float4*)&s1[l][tj * 4];
    const float av[4] = {a4.x, a4.y, a4.z, a4.w};
    const float bv[4] = {b4.x, b4.y, b4.z, b4.w};
    #pragma unroll
    for (int a = 0; a < 4; ++a)
      #pragma unroll
      for (int b = 0; b < 4; ++b) acc[a][b] += av[a] * bv[b];
  }

  float tf[4][4];
  #pragma unroll
  for (int a = 0; a < 4; ++a)
    #pragma unroll
    for (int b = 0; b < 4; ++b) tf[a][b] = tanh_fast(acc[a][b]);

  // scaled softmax weights at the j-columns (w1) and i-columns (w2)
  float w1j[4], w2i[4];
  #pragma unroll
  for (int b = 0; b < 4; ++b)
    w1j[b] = WSCALE_ * __expf(cval[(size_t)b1 * HW_ + j0 + tj * 4 + b] - m1) * rl1;
  #pragma unroll
  for (int a = 0; a < 4; ++a)
    w2i[a] = WSCALE_ * __expf(cval[(size_t)b2 * HW_ + i0 + ti * 4 + a] - m2) * rl2;

  unsigned short* __restrict__ An  = Abf  + ((size_t)n << 20);
  unsigned short* __restrict__ Atn = Atbf + ((size_t)n << 20);
  // Abf[i][j] = s*w1[j]*A[i][j] : direct coalesced rows
  #pragma unroll
  for (int a = 0; a < 4; ++a){
    ushort4 va;
    va.x = f2h(tf[a][0] * w1j[0]); va.y = f2h(tf[a][1] * w1j[1]);
    va.z = f2h(tf[a][2] * w1j[2]); va.w = f2h(tf[a][3] * w1j[3]);
    *(ushort4*)&An[(size_t)(i0 + ti * 4 + a) * HW_ + j0 + tj * 4] = va;
  }
  // Atn[u=j][v=i] = s*w2[i]*A[i][j] : stage in LDS, write full rows
  #pragma unroll
  for (int b = 0; b < 4; ++b){
    ushort4 vb;
    vb.x = f2h(tf[0][b] * w2i[0]); vb.y = f2h(tf[1][b] * w2i[1]);
    vb.z = f2h(tf[2][b] * w2i[2]); vb.w = f2h(tf[3][b] * w2i[3]);
    *(ushort4*)&at_s[tj * 4 + b][ti * 4] = vb;
  }
  __syncthreads();
  #pragma unroll
  for (int rep = 0; rep < 2; ++rep){
    const int idx = t + rep * 256;
    const int r = idx >> 3, q = (idx & 7) * 8;
    const ushort4 lo = *(const ushort4*)&at_s[r][q];
    const ushort4 hi = *(const ushort4*)&at_s[r][q + 4];
    *(ushort4*)&Atn[(size_t)(j0 + r) * HW_ + i0 + q] = lo;
    *(ushort4*)&Atn[(size_t)(j0 + r) * HW_ + i0 + q + 4] = hi;
  }
}

// K3: fused MFMA GEMM + channel-L2-norm + residual/ReLU.
// 3-deep LDS pipeline with counted vmcnt (never drains to 0 mid-loop) + raw s_barrier
// so prefetched global_load_lds stay in flight across barriers (T3/T4).
__global__ __launch_bounds__(512) void k_gemm_fused(
    const _Float16* __restrict__ fhc1, const _Float16* __restrict__ fhc2,
    const unsigned short* __restrict__ Abf, const unsigned short* __restrict__ Atbf,
    const float* __restrict__ fpin1, const float* __restrict__ fpin2,
    float* __restrict__ fpo1, float* __restrict__ fpo2,
    _Float16* __restrict__ fhn1, _Float16* __restrict__ fhn2,
    float* __restrict__ out, int last)
{
  const int n = blockIdx.z, g = blockIdx.y, i0 = blockIdx.x * 64;
  const unsigned short* __restrict__ X =
      (const unsigned short*)((g ? fhc2 : fhc1) + (size_t)n * C_ * HW_);
  const unsigned short* __restrict__ B = (g ? Atbf : Abf) + ((size_t)n << 20);

  __shared__ unsigned short Xs[3][256 * 64];  // 3 x 32 KB
  __shared__ unsigned short Bs[3][64 * 64];   // 3 x 8 KB
  __shared__ float ssred[4][64];
  __shared__ float rinv[64];

  const int t = threadIdx.x, w = t >> 6, l = t & 63;
  const int wr = w >> 1, wc = w & 1;

  f32x4 acc[4][2];
  #pragma unroll
  for (int fm = 0; fm < 4; ++fm)
    #pragma unroll
    for (int fn = 0; fn < 2; ++fn)
      acc[fm][fn] = (f32x4){0.f, 0.f, 0.f, 0.f};

  // per wave: 4 X-chunk loads + 1 B-chunk load = 5 VMEM ops per stage
  auto stage = [&](int buf, int k0){
    #pragma unroll
    for (int s = 0; s < 4; ++s){
      const int q = (w * 4 + s) * 64 + l;
      const int row = q >> 3;
      const int kc = (q & 7) ^ (row & 7);
      GLD16(X + (size_t)row * HW_ + k0 + kc * 8, &Xs[buf][(w * 4 + s) * 512]);
    }
    {
      const int q = w * 64 + l;
      const int row = q >> 3;
      const int kc = (q & 7) ^ (row & 7);
      GLD16(B + (size_t)(i0 + row) * HW_ + k0 + kc * 8, &Bs[buf][w * 512]);
    }
  };

  // prologue: 3 tiles in flight (15 VMEM ops outstanding per wave)
  stage(0, 0);
  stage(1, 64);
  stage(2, 128);

  int cur = 0;
  for (int kt = 0; kt < 16; ++kt){
    // wait ONLY for tile kt's 5 loads (leave later tiles in flight)
    if (kt < 14)      { asm volatile("s_waitcnt vmcnt(10)" ::: "memory"); }
    else if (kt == 14){ asm volatile("s_waitcnt vmcnt(5)"  ::: "memory"); }
    else              { asm volatile("s_waitcnt vmcnt(0)"  ::: "memory"); }
    __builtin_amdgcn_sched_barrier(0);
    __builtin_amdgcn_s_barrier();   // all waves' tile-kt loads landed in LDS

    #pragma unroll
    for (int ks = 0; ks < 2; ++ks){
      half8 a[4], b[2];
      #pragma unroll
      for (int fm = 0; fm < 4; ++fm){
        const int row = wr * 64 + fm * 16 + (l & 15);
        const int kc = (ks * 4 + (l >> 4)) ^ (row & 7);
        a[fm] = *(const half8*)&Xs[cur][row * 64 + kc * 8];
      }
      #pragma unroll
      for (int fn = 0; fn < 2; ++fn){
        const int row = wc * 32 + fn * 16 + (l & 15);
        const int kc = (ks * 4 + (l >> 4)) ^ (row & 7);
        b[fn] = *(const half8*)&Bs[cur][row * 64 + kc * 8];
      }
      #pragma unroll
      for (int fm = 0; fm < 4; ++fm)
        #pragma unroll
        for (int fn = 0; fn < 2; ++fn)
          acc[fm][fn] = __builtin_amdgcn_mfma_f32_16x16x32_f16(a[fm], b[fn], acc[fm][fn], 0, 0, 0);
    }

    asm volatile("s_waitcnt lgkmcnt(0)" ::: "memory");  // all my ds_reads of buf cur done
    __builtin_amdgcn_sched_barrier(0);
    __builtin_amdgcn_s_barrier();   // all waves done reading buf cur
    __builtin_amdgcn_sched_barrier(0);

    if (kt < 13) stage(cur, (kt + 3) * 64);   // refill buf cur with tile kt+3
    cur = (cur == 2) ? 0 : cur + 1;
  }

  // fused epilogue: column L2 norm over all 256 channels (scale s cancels)
  float ss0 = 0.f, ss1 = 0.f;
  #pragma unroll
  for (int fm = 0; fm < 4; ++fm)
    #pragma unroll
    for (int r = 0; r < 4; ++r){
      ss0 += acc[fm][0][r] * acc[fm][0][r];
      ss1 += acc[fm][1][r] * acc[fm][1][r];
    }
  ss0 += __shfl_xor(ss0, 16); ss0 += __shfl_xor(ss0, 32);
  ss1 += __shfl_xor(ss1, 16); ss1 += __shfl_xor(ss1, 32);
  if (l < 16){
    ssred[wr][wc * 32 + l]      = ss0;
    ssred[wr][wc * 32 + 16 + l] = ss1;
  }
  __syncthreads();
  if (t < 64)
    rinv[t] = 1.f / fmaxf(sqrtf(ssred[0][t] + ssred[1][t] + ssred[2][t] + ssred[3][t]), 1e-12f);
  __syncthreads();

  const float ri[2] = { rinv[wc * 32 + (l & 15)], rinv[wc * 32 + 16 + (l & 15)] };

  const float* __restrict__ fpin = (g ? fpin2 : fpin1) + (size_t)n * C_ * HW_;
  float* __restrict__ fpo  = (g ? fpo2 : fpo1) + (size_t)n * C_ * HW_;
  _Float16* __restrict__ fhn = (g ? fhn2 : fhn1) + (size_t)n * C_ * HW_;
  float* __restrict__ outp = out + (size_t)g * SZ_ + (size_t)n * C_ * HW_;
  const int rbase = (l >> 4) * 4, col = l & 15;

  #pragma unroll
  for (int fm = 0; fm < 4; ++fm)
    #pragma unroll
    for (int fn = 0; fn < 2; ++fn){
      const size_t base = (size_t)(wr * 64 + fm * 16 + rbase) * HW_ + i0 + wc * 32 + fn * 16 + col;
      #pragma unroll
      for (int r = 0; r < 4; ++r){
        const float h = acc[fm][fn][r] * ri[fn];
        if (last) outp[base + (size_t)r * HW_] = h;
        else {
          const float fv = fpin[base + (size_t)r * HW_] + h;
          const float rv = fv > 0.f ? fv : 0.f;
          fpo[base + (size_t)r * HW_] = rv;
          fhn[base + (size_t)r * HW_] = (_Float16)rv;
        }
      }
    }
}

// K_s: s[n,c,hw] = w * fp (fp32 state),  w = exp(cval - m) * rl
__global__ __launch_bounds__(256) void k_s_out(
    const float* __restrict__ fp1, const float* __restrict__ fp2,
    const float* __restrict__ cval,
    const float* __restrict__ mpart, const float* __restrict__ spart,
    float* __restrict__ out)
{
  const int side = blockIdx.y;
  const size_t fo = ((size_t)blockIdx.x * 256 + threadIdx.x) * 4;
  const float* __restrict__ f = side ? fp2 : fp1;
  const int n  = (int)(fo >> 18);
  const int hw = (int)(fo & (HW_ - 1));
  const int base = n * 2 + side;
  float m, rl;
  combine16(mpart, spart, base, m, rl);
  const float4 c = *(const float4*)&cval[(size_t)base * HW_ + hw];
  const float4 v = *(const float4*)&f[fo];
  float4 r;
  r.x = v.x * (__expf(c.x - m) * rl);
  r.y = v.y * (__expf(c.y - m) * rl);
  r.z = v.z * (__expf(c.z - m) * rl);
  r.w = v.w * (__expf(c.w - m) * rl);
  *(float4*)&out[(size_t)(2 + side) * SZ_ + fo] = r;
}

extern "C" void kernel_launch(void* const* d_in, const int* in_sizes, int n_in,
                              void* d_out, int out_size, void* d_ws, size_t ws_size,
                              hipStream_t stream)
{
  const float* f1  = (const float*)d_in[0];
  const float* f2  = (const float*)d_in[1];
  const float* pw1 = (const float*)d_in[2];
  const float* pb1 = (const float*)d_in[3];
  const float* pw2 = (const float*)d_in[4];
  const float* pb2 = (const float*)d_in[5];
  const float* cw1 = (const float*)d_in[6];
  const float* cw2 = (const float*)d_in[8];
  // cb1/cb2 unused: softmax is shift-invariant
  float* out = (float*)d_out;
  float* ws  = (float*)d_ws;

  float* cval  = ws;                           // 16K f32
  float* pdot  = cval + N_ * 2 * HW_;          // 256K f32
  float* mpart = pdot + N_ * 2 * CL_ * HW_;    // 512
  float* spart = mpart + 512;                  // 512
  float* fp1   = spart + 512;                  // SZ_ f32 state
  float* fp2   = fp1 + SZ_;                    // SZ_ f32 state
  _Float16* fhA1 = (_Float16*)(fp2 + SZ_);     // SZ_ fp16 mirror (ping)
  _Float16* fhA2 = fhA1 + SZ_;
  _Float16* fhB1 = fhA2 + SZ_;                 // SZ_ fp16 mirror (pong)
  _Float16* fhB2 = fhB1 + SZ_;
  unsigned short* Abf  = (unsigned short*)(fhB2 + SZ_);  // 8M fp16
  unsigned short* Atbf = Abf + ((size_t)N_ << 20);       // 8M fp16

  k_cvt<<<dim3(SZ_ / 8 / 256, 2), 256, 0, stream>>>(f1, f2, fhA1, fhA2);

  for (int it = 0; it < 5; ++it){
    const float* cur1 = (it == 0) ? f1 : fp1;
    const float* cur2 = (it == 0) ? f2 : fp2;
    const _Float16* fhc1 = (it & 1) ? fhB1 : fhA1;
    const _Float16* fhc2 = (it & 1) ? fhB2 : fhA2;
    _Float16* fhn1 = (it & 1) ? fhA1 : fhB1;
    _Float16* fhn2 = (it & 1) ? fhA2 : fhB2;

    k_sa_dot<<<dim3(16, 2, 8), 256, 0, stream>>>(cur1, cur2, cw1, cw2, pw1, pw2,
                                                 cval, pdot, mpart, spart);
    if (it == 4)
      k_s_out<<<dim3(SZ_ / 4 / 256, 2), 256, 0, stream>>>(cur1, cur2, cval, mpart, spart, out);
    k_corr<<<dim3(16, 16, 8), 256, 0, stream>>>(cval, pdot, pb1, pb2, mpart, spart, Abf, Atbf);
    k_gemm_fused<<<dim3(16, 2, 8), 512, 0, stream>>>(fhc1, fhc2, Abf, Atbf,
                                                     cur1, cur2, fp1, fp2, fhn1, fhn2,
                                                     out, (it == 4) ? 1 : 0);
  }
}